// Round 3
// baseline (87.144 us; speedup 1.0000x reference)
//
#include <hip/hip_runtime.h>
#include <math.h>

#define NB 512
#define NS 64
#define ND 2048
#define NP 1024   // ND/2

// ws layout (float offsets)
#define OFF_M0   0         // 131072
#define OFF_M1   131072    // 131072
#define OFF_QT   262144    // float4[1024][64]      = 262144 floats
#define OFF_RT   524288    // float2[1024][64]      = 131072 floats
#define OFF_W    655360    // 64*64                 = 4096
#define OFF_PART 659456    // [8][512][64]          = 262144 floats

// ---------------- threefry2x32 (exact jax semantics, key=(0,42)) -------------
__device__ __forceinline__ unsigned rotl32(unsigned x, int d) {
    return (x << d) | (x >> (32 - d));
}

__device__ __forceinline__ void threefry2x32(unsigned k0, unsigned k1,
                                             unsigned& x0, unsigned& x1) {
    const unsigned ks0 = k0, ks1 = k1, ks2 = k0 ^ k1 ^ 0x1BD11BDAu;
    const int r0[4] = {13, 15, 26, 6};
    const int r1[4] = {17, 29, 16, 24};
    x0 += ks0; x1 += ks1;
#pragma unroll
    for (int i = 0; i < 4; ++i) { x0 += x1; x1 = rotl32(x1, r0[i]); x1 ^= x0; }
    x0 += ks1; x1 += ks2 + 1u;
#pragma unroll
    for (int i = 0; i < 4; ++i) { x0 += x1; x1 = rotl32(x1, r1[i]); x1 ^= x0; }
    x0 += ks2; x1 += ks0 + 2u;
#pragma unroll
    for (int i = 0; i < 4; ++i) { x0 += x1; x1 = rotl32(x1, r0[i]); x1 ^= x0; }
    x0 += ks0; x1 += ks1 + 3u;
#pragma unroll
    for (int i = 0; i < 4; ++i) { x0 += x1; x1 = rotl32(x1, r1[i]); x1 ^= x0; }
    x0 += ks1; x1 += ks2 + 4u;
#pragma unroll
    for (int i = 0; i < 4; ++i) { x0 += x1; x1 = rotl32(x1, r0[i]); x1 ^= x0; }
    x0 += ks2; x1 += ks0 + 5u;
}

// ---------------- K0: per-row norm + softmax(E row) + RT[p][t] ---------------
// 64 blocks x 256 threads; block t handles amp row t + E row t.
// Writes R TRANSPOSED (RT[p][t] float2) so k_MQ reads contiguous 128 B/thread.
__global__ void __launch_bounds__(256)
k_pre(const float* __restrict__ amp, const float* __restrict__ ph,
      const float* __restrict__ E, float* __restrict__ RT,
      float* __restrict__ W) {
    __shared__ float in_sh;
    const int t = blockIdx.x;
    const int tid = threadIdx.x;

    if (tid < 16) {  // wave 0: norm of amp row t (exact original summation order)
        const float4* a4 = (const float4*)(amp + t * ND);
        float acc = 0.f;
#pragma unroll 8
        for (int i = 0; i < 32; ++i) {
            float4 v = a4[tid + 16 * i];
            acc += v.x * v.x + v.y * v.y + v.z * v.z + v.w * v.w;
        }
        acc += __shfl_down(acc, 8, 16);
        acc += __shfl_down(acc, 4, 16);
        acc += __shfl_down(acc, 2, 16);
        acc += __shfl_down(acc, 1, 16);
        if (tid == 0) in_sh = 1.0f / sqrtf(acc);
    }
    if (tid >= 64 && tid < 128) {  // wave 1: softmax of E row t (exact original)
        const int s = tid - 64;
        float e = E[t * NS + s];
        float m = e;
        for (int off = 32; off; off >>= 1) m = fmaxf(m, __shfl_down(m, off));
        m = __shfl(m, 0);
        float ex = expf(e - m);
        float sum = ex;
        for (int off = 32; off; off >>= 1) sum += __shfl_down(sum, off);
        sum = __shfl(sum, 0);
        W[t * NS + s] = ex / sum;
    }
    __syncthreads();

    const float in = in_sh;
    const float2* a2 = (const float2*)(amp + t * ND);
    const float2* p2 = (const float2*)(ph + t * ND);
    float2* rT = (float2*)RT;
#pragma unroll
    for (int k = 0; k < 4; ++k) {
        const int i = tid + 256 * k;   // pair index
        float2 av = a2[i], pv = p2[i];
        float2 rv;
        rv.x = av.x * in * (__cosf(pv.x) + __sinf(pv.x));
        rv.y = av.y * in * (__cosf(pv.y) + __sinf(pv.y));
        rT[(i << 6) + t] = rv;         // transposed scatter (512 KB total)
    }
}

// ---------------- K1: M0/M1/Qt4 from RT, W -----------------------------------
// 1024 blocks x 256 threads: srow = blk>>4, pc = blk&15 (64-pair chunks).
// Thread = (pair pi, t-group tg of 16); per thread 8 contiguous dwordx4 loads
// of RT (full MLP), 4x16+ordered-combine summation shape as before.
__global__ void __launch_bounds__(256)
k_MQ(const float* __restrict__ RT, const float* __restrict__ W,
     const float* __restrict__ G,
     float* __restrict__ M0, float* __restrict__ M1, float* __restrict__ Qt) {
    __shared__ float WG[NS * 4];       // WG[4t+k] = W[srow][t]*G[t][k]
    __shared__ float4 part4[4][64];
    const int blk = blockIdx.x;
    const int srow = blk >> 4, pc = blk & 15;
    const int tid = threadIdx.x;

    WG[tid] = W[srow * NS + (tid >> 2)] * G[tid];
    __syncthreads();

    const int pi = tid & 63, tg = tid >> 6;
    const int p = (pc << 6) + pi;
    const float4* rt = (const float4*)RT + p * 32 + tg * 8;  // 16 t = 8 float4
    float a0 = 0.f, a1 = 0.f, b0 = 0.f, b1 = 0.f;
#pragma unroll
    for (int i = 0; i < 8; ++i) {
        float4 rv = rt[i];
        const int tb = (tg << 6) + (i << 3);   // = 4*t, t = tg*16 + 2i
        a0 += rv.x * WG[tb + 0]; b0 += rv.x * WG[tb + 2];
        a1 += rv.y * WG[tb + 1]; b1 += rv.y * WG[tb + 3];
        a0 += rv.z * WG[tb + 4]; b0 += rv.z * WG[tb + 6];
        a1 += rv.w * WG[tb + 5]; b1 += rv.w * WG[tb + 7];
    }
    part4[tg][pi] = make_float4(a0, a1, b0, b1);
    __syncthreads();

    if (tid < 64) {  // ordered combine, write M0/M1 + padded Qt float4
        float4 s0 = part4[0][tid], s1 = part4[1][tid],
               s2 = part4[2][tid], s3 = part4[3][tid];
        float A0 = s0.x + s1.x + s2.x + s3.x;
        float A1 = s0.y + s1.y + s2.y + s3.y;
        float B0 = s0.z + s1.z + s2.z + s3.z;
        float B1 = s0.w + s1.w + s2.w + s3.w;
        const int P = (pc << 6) + tid;
        ((float2*)(M0 + srow * ND))[P] = make_float2(A0, A1);
        ((float2*)(M1 + srow * ND))[P] = make_float2(B0, B1);
        ((float4*)Qt)[P * 64 + srow] =
            make_float4(A0 * A0 + A1 * A1, A0 * B0 + A1 * B1, B0 * B0 + B1 * B1, 0.f);
    }
}

// ---------------- K2a: partial logits (8 rows x 1/8 p-range) -----------------
// 512 blocks x 1024 threads: rg = blk>>3 (rows rg*8..+8), pc = blk&7
// (128-pair chunk). Wave w owns 8 pl; Qt read = one aligned dwordx4/lane,
// wave-contiguous 1 KB. j-loop rotated by rg to de-camp L2.
__global__ void __launch_bounds__(1024)
k_logA(const float* __restrict__ x, const float* __restrict__ Qt,
       float* __restrict__ pglob) {
    __shared__ float4 xq[8][128];       // 16 KB
    __shared__ float part[16][8][64];   // 32 KB
    const int blk = blockIdx.x;
    const int tid = threadIdx.x;
    const int rg = blk >> 3, pc = blk & 7;
    const int r0 = rg * 8;

    if (tid < 512) {   // stage x chunk in quadratic form (coalesced float4)
        const int r = tid >> 6, i = tid & 63;
        float4 v = ((const float4*)(x + (r0 + r) * ND + pc * 256))[i];
        float4 q0, q1;
        q0.x = v.x * v.x; q0.y = 2.f * v.x * v.y; q0.z = v.y * v.y; q0.w = 0.f;
        q1.x = v.z * v.z; q1.y = 2.f * v.z * v.w; q1.z = v.w * v.w; q1.w = 0.f;
        xq[r][2 * i] = q0;
        xq[r][2 * i + 1] = q1;
    }
    __syncthreads();

    const int w = tid >> 6, s = tid & 63;
    float acc[8] = {0.f, 0.f, 0.f, 0.f, 0.f, 0.f, 0.f, 0.f};
    const float4* qt4 = (const float4*)Qt + (pc * 128 + (w << 3)) * 64 + s;
#pragma unroll
    for (int j = 0; j < 8; ++j) {
        const int jj = (j + rg) & 7;            // skewed visit order
        const int pl = (w << 3) + jj;
        float4 q = qt4[jj * 64];                // aligned dwordx4, 1 KB/wave
#pragma unroll
        for (int r = 0; r < 8; ++r) {
            float4 xv = xq[r][pl];              // LDS broadcast
            acc[r] += xv.x * q.x + xv.y * q.y + xv.z * q.z;
        }
    }
#pragma unroll
    for (int r = 0; r < 8; ++r) part[w][r][s] = acc[r];
    __syncthreads();

    if (tid < 512) {  // cross-wave reduce (fixed order), publish partial slot
        const int rr = tid >> 6;
        float l = 0.f;
#pragma unroll
        for (int k = 0; k < 16; ++k) l += part[k][rr][s];
        pglob[(pc * NB + r0 + rr) * NS + s] = l;
    }
}

// ---------------- K2b: final logits + collapse + output; 1 row/block ---------
// 512 blocks x 512 threads. Fixed-order reduce of 8 slots, exact jax
// categorical, pure-float4 gather/write.
__global__ void __launch_bounds__(512)
k_logB(const float* __restrict__ x, const float* __restrict__ pglob,
       const float* __restrict__ M0, const float* __restrict__ M1,
       float* __restrict__ out) {
    __shared__ int o_sh;
    const int r = blockIdx.x;
    const int tid = threadIdx.x;

    if (tid < 64) {  // wave 0: reduce slots + gumbel-max
        const int s = tid;
        float l = 0.f;
#pragma unroll
        for (int c = 0; c < 8; ++c) l += pglob[(c * NB + r) * NS + s];
        unsigned n = (unsigned)(r * NS + s);
        unsigned t0u = 0u, t1u = n;
        threefry2x32(0u, 42u, t0u, t1u);
        unsigned bits = t0u ^ t1u;
        float u = (float)(bits >> 9) * (1.0f / 8388608.0f);
        u = fmaxf(u, 1.17549435e-38f);
        float g = -logf(-logf(u));
        float best = l + g;
        int bi = s;
        for (int off = 32; off; off >>= 1) {
            float ov = __shfl_down(best, off);
            int oi = __shfl_down(bi, off);
            if (ov > best || (ov == best && oi < bi)) { best = ov; bi = oi; }
        }
        if (s == 0) o_sh = bi;
    }
    __syncthreads();

    const int o = o_sh;
    float4 xv = ((const float4*)(x + r * ND))[tid];
    float4 m0 = ((const float4*)(M0 + o * ND))[tid];
    float4 m1 = ((const float4*)(M1 + o * ND))[tid];
    float4 rr;
    rr.x = xv.x * m0.x + xv.y * m1.x;
    rr.y = xv.x * m0.y + xv.y * m1.y;
    rr.z = xv.z * m0.z + xv.w * m1.z;
    rr.w = xv.z * m0.w + xv.w * m1.w;
    ((float4*)(out + r * ND))[tid] = rr;
}

extern "C" void kernel_launch(void* const* d_in, const int* in_sizes, int n_in,
                              void* d_out, int out_size, void* d_ws, size_t ws_size,
                              hipStream_t stream) {
    const float* x   = (const float*)d_in[0];  // [512,2048]
    const float* amp = (const float*)d_in[1];  // [64,2048]
    const float* ph  = (const float*)d_in[2];  // [64,2048]
    const float* G   = (const float*)d_in[3];  // [64,2,2]
    const float* E   = (const float*)d_in[4];  // [64,64]
    float* out = (float*)d_out;
    float* ws = (float*)d_ws;

    float* M0 = ws + OFF_M0;
    float* M1 = ws + OFF_M1;
    float* Qt = ws + OFF_QT;
    float* RT = ws + OFF_RT;
    float* W  = ws + OFF_W;
    float* pp = ws + OFF_PART;

    k_pre <<<64, 256, 0, stream>>>(amp, ph, E, RT, W);
    k_MQ  <<<1024, 256, 0, stream>>>(RT, W, G, M0, M1, Qt);
    k_logA<<<512, 1024, 0, stream>>>(x, Qt, pp);
    k_logB<<<512, 512, 0, stream>>>(x, pp, M0, M1, out);
}